// Round 4
// baseline (440.170 us; speedup 1.0000x reference)
//
#include <hip/hip_runtime.h>
#include <hip/hip_fp16.h>

#define BB 2
#define DX 160
#define DY 160
#define DZ 160

constexpr int    VOL        = DX * DY * DZ;          // 4,096,000
constexpr int    NVOX       = BB * VOL;              // 8,192,000
constexpr size_t PACK_BYTES = (size_t)NVOX * 32;     // 262,144,000 B

// ---------------------------------------------------------------------------
// Pack v2: one thread per 8-cell z-segment. Cell (b,x,y,z) -> 8 corners x 2ch
// fp16, corner order c = ix*4 + iy*2 + iz, each corner a __half2 (ch0,ch1).
// Cell = 32 B. Thread reads 4 corner rows (x/x1 × y/y1) as 4×float4 + float2,
// converts each row's 9 voxel-pairs to half2 ONCE (shared by z-adjacent
// cells), writes 8 cells = 256 B contiguous.
// ---------------------------------------------------------------------------
__global__ __launch_bounds__(256) void pack_kernel(const float* __restrict__ im,
                                                   float4* __restrict__ pk)
{
    constexpr int NSEG = DZ / 8;                     // 20 segments per row
    constexpr int NT   = BB * DX * DY * NSEG;        // 1,024,000 threads
    int t = blockIdx.x * blockDim.x + threadIdx.x;
    if (t >= NT) return;

    int k = t % NSEG;
    int r = t / NSEG;
    int y = r % DY;  r /= DY;
    int x = r % DX;
    int b = r / DX;

    const int z0 = 8 * k;
    const int x1 = min(x + 1, DX - 1);
    const int y1 = min(y + 1, DY - 1);
    const int z8 = min(z0 + 8, DZ - 1);              // clamped 9th voxel

    const float2* __restrict__ imf = (const float2*)im;

    // rows indexed rr = ix + 2*iy
    const int row[4] = {
        ((b * DX + x ) * DY + y ) * DZ,
        ((b * DX + x1) * DY + y ) * DZ,
        ((b * DX + x ) * DY + y1) * DZ,
        ((b * DX + x1) * DY + y1) * DZ
    };

    __half2 h[4][9];
#pragma unroll
    for (int rr = 0; rr < 4; ++rr) {
        const float4* p = (const float4*)(imf + row[rr] + z0);  // 16B aligned
        const float4 q0 = p[0];
        const float4 q1 = p[1];
        const float4 q2 = p[2];
        const float4 q3 = p[3];
        const float2 e  = imf[row[rr] + z8];
        h[rr][0] = __floats2half2_rn(q0.x, q0.y);
        h[rr][1] = __floats2half2_rn(q0.z, q0.w);
        h[rr][2] = __floats2half2_rn(q1.x, q1.y);
        h[rr][3] = __floats2half2_rn(q1.z, q1.w);
        h[rr][4] = __floats2half2_rn(q2.x, q2.y);
        h[rr][5] = __floats2half2_rn(q2.z, q2.w);
        h[rr][6] = __floats2half2_rn(q3.x, q3.y);
        h[rr][7] = __floats2half2_rn(q3.z, q3.w);
        h[rr][8] = __floats2half2_rn(e.x,  e.y);
    }

    float4* dst = pk + (size_t)(row[0] + z0) * 2;    // 256 B contiguous
#pragma unroll
    for (int j = 0; j < 8; ++j) {
        // corner c = ix*4 + iy*2 + iz ; rr for (ix,iy): c0/c1->rr0, c2/c3->rr2,
        // c4/c5->rr1, c6/c7->rr3
        __half2 lo[4] = { h[0][j], h[0][j + 1], h[2][j], h[2][j + 1] };
        __half2 hi[4] = { h[1][j], h[1][j + 1], h[3][j], h[3][j + 1] };
        dst[2 * j]     = *(const float4*)lo;
        dst[2 * j + 1] = *(const float4*)hi;
    }
}

// ---------------------------------------------------------------------------
// Gather (round-2 known-good): one 32 B cell read per voxel, 2 voxels/thread.
// ---------------------------------------------------------------------------
__device__ __forceinline__ float2 trilerp_cell(const float4 A, const float4 B,
                                               float xd, float yd, float zd)
{
    union { float4 f4[2]; __half2 h2[8]; } u;
    u.f4[0] = A;
    u.f4[1] = B;

    const float xm = 1.0f - xd, ym = 1.0f - yd, zm = 1.0f - zd;
    const float wx[2] = { xm, xd };
    const float wy[2] = { ym, yd };
    const float wz[2] = { zm, zd };

    float rx = 0.0f, ry = 0.0f;
#pragma unroll
    for (int c = 0; c < 8; ++c) {
        const float w = wx[(c >> 2) & 1] * wy[(c >> 1) & 1] * wz[c & 1];
        const float2 v = __half22float2(u.h2[c]);
        rx += w * v.x;
        ry += w * v.y;
    }
    return make_float2(rx, ry);
}

__global__ __launch_bounds__(256) void gather_kernel(const float4* __restrict__ pk,
                                                     const float* __restrict__ defgrid,
                                                     float2* __restrict__ out)
{
    constexpr int HALF = NVOX / 2;
    const int t = blockIdx.x * blockDim.x + threadIdx.x;
    if (t >= HALF) return;

    const int i0 = t;
    const int i1 = t + HALF;

    const float x0f = defgrid[(size_t)i0 * 3 + 0];
    const float y0f = defgrid[(size_t)i0 * 3 + 1];
    const float z0f = defgrid[(size_t)i0 * 3 + 2];
    const float x1f = defgrid[(size_t)i1 * 3 + 0];
    const float y1f = defgrid[(size_t)i1 * 3 + 1];
    const float z1f = defgrid[(size_t)i1 * 3 + 2];

    const int ax = min(max((int)floorf(x0f), 0), DX - 1);
    const int ay = min(max((int)floorf(y0f), 0), DY - 1);
    const int az = min(max((int)floorf(z0f), 0), DZ - 1);
    const int bx = min(max((int)floorf(x1f), 0), DX - 1);
    const int by = min(max((int)floorf(y1f), 0), DY - 1);
    const int bz = min(max((int)floorf(z1f), 0), DZ - 1);

    const size_t cell0 = ((size_t)((      ax) * DY + ay) * DZ + az) * 2;           // b=0
    const size_t cell1 = ((size_t)(((DX + bx)) * DY + by) * DZ + bz) * 2;          // b=1

    const float4 A0 = pk[cell0];
    const float4 B0 = pk[cell0 + 1];
    const float4 A1 = pk[cell1];
    const float4 B1 = pk[cell1 + 1];

    const float2 r0 = trilerp_cell(A0, B0, x0f - (float)ax, y0f - (float)ay, z0f - (float)az);
    const float2 r1 = trilerp_cell(A1, B1, x1f - (float)bx, y1f - (float)by, z1f - (float)bz);

    out[i0] = r0;
    out[i1] = r1;
}

// ---------------------------------------------------------------------------
// Fallback direct kernel in case ws_size < PACK_BYTES.
// ---------------------------------------------------------------------------
__global__ __launch_bounds__(256) void trilerp3d_direct(
    const float* __restrict__ im,
    const float* __restrict__ defgrid,
    float*       __restrict__ out)
{
    int idx = blockIdx.x * blockDim.x + threadIdx.x;
    if (idx >= NVOX) return;

    const float x = defgrid[idx * 3 + 0];
    const float y = defgrid[idx * 3 + 1];
    const float z = defgrid[idx * 3 + 2];

    const int x0u = (int)floorf(x);
    const int y0u = (int)floorf(y);
    const int z0u = (int)floorf(z);

    const int x0 = min(max(x0u, 0), DX - 1);
    const int x1 = min(max(x0u + 1, 0), DX - 1);
    const int y0 = min(max(y0u, 0), DY - 1);
    const int y1 = min(max(y0u + 1, 0), DY - 1);
    const int z0 = min(max(z0u, 0), DZ - 1);
    const int z1 = min(max(z0u + 1, 0), DZ - 1);

    const float xd = x - (float)x0;
    const float yd = y - (float)y0;
    const float zd = z - (float)z0;

    const int b    = idx / VOL;
    const int base = b * VOL;

    const float2* __restrict__ imf = (const float2*)im;

    const int px0 = base + x0 * (DY * DZ);
    const int px1 = base + x1 * (DY * DZ);
    const int oy0 = y0 * DZ;
    const int oy1 = y1 * DZ;

    const float2 Ia = imf[px0 + oy0 + z0];
    const float2 Ib = imf[px0 + oy0 + z1];
    const float2 Ic = imf[px0 + oy1 + z0];
    const float2 Id = imf[px0 + oy1 + z1];
    const float2 Ie = imf[px1 + oy0 + z0];
    const float2 If = imf[px1 + oy0 + z1];
    const float2 Ig = imf[px1 + oy1 + z0];
    const float2 Ih = imf[px1 + oy1 + z1];

    const float xm = 1.0f - xd, ym = 1.0f - yd, zm = 1.0f - zd;

    float cae_x = Ia.x * xm + Ie.x * xd;
    float cae_y = Ia.y * xm + Ie.y * xd;
    float cbf_x = Ib.x * xm + If.x * xd;
    float cbf_y = Ib.y * xm + If.y * xd;
    float ccg_x = Ic.x * xm + Ig.x * xd;
    float ccg_y = Ic.y * xm + Ig.y * xd;
    float cdh_x = Id.x * xm + Ih.x * xd;
    float cdh_y = Id.y * xm + Ih.y * xd;

    float c0_x = cae_x * ym + ccg_x * yd;
    float c0_y = cae_y * ym + ccg_y * yd;
    float c1_x = cbf_x * ym + cdh_x * yd;
    float c1_y = cbf_y * ym + cdh_y * yd;

    float2 r;
    r.x = c0_x * zm + c1_x * zd;
    r.y = c0_y * zm + c1_y * zd;
    ((float2*)out)[idx] = r;
}

extern "C" void kernel_launch(void* const* d_in, const int* in_sizes, int n_in,
                              void* d_out, int out_size, void* d_ws, size_t ws_size,
                              hipStream_t stream) {
    const float* im      = (const float*)d_in[0];
    const float* defgrid = (const float*)d_in[1];
    float*       out     = (float*)d_out;

    const int block = 256;

    if (ws_size >= PACK_BYTES) {
        float4* pk = (float4*)d_ws;
        constexpr int NTP = BB * DX * DY * (DZ / 8);
        const int gridP = (NTP + block - 1) / block;
        pack_kernel<<<gridP, block, 0, stream>>>(im, pk);
        const int gridG = (NVOX / 2 + block - 1) / block;
        gather_kernel<<<gridG, block, 0, stream>>>(pk, defgrid, (float2*)out);
    } else {
        const int grid = (NVOX + block - 1) / block;
        trilerp3d_direct<<<grid, block, 0, stream>>>(im, defgrid, out);
    }
}